// Round 3
// baseline (225.935 us; speedup 1.0000x reference)
//
#include <hip/hip_runtime.h>
#include <hip/hip_bf16.h>

#define D_FEAT 128
#define D4 (D_FEAT / 4)
#define MAXBLK 64              // max 1024-wide scan blocks -> N <= 65536

// ---- K1: blocks < 256: grid-stride node histogram via global atomics
//      (cnt[] pre-zeroed by memset); blocks >= 256: fp32 -> bf16 feature
//      table, fb16[n*64+k] = (f[2k], f[2k+1]).
__global__ __launch_bounds__(256) void k1_hist_cvt(
        const int* __restrict__ dst, int E,
        int* __restrict__ cnt,
        const float4* __restrict__ fin, __hip_bfloat162* __restrict__ fout,
        int n4) {
    int c = blockIdx.x;
    int tid = threadIdx.x;
    if (c < 256) {
        int idx = c * 256 + tid;
        for (int i = idx; i < E; i += 256 * 256)
            atomicAdd(&cnt[dst[i]], 1);
    } else {
        int idx = (c - 256) * 256 + tid;
        int stride = (gridDim.x - 256) * 256;
        for (int i = idx; i < n4; i += stride) {
            float4 f = fin[i];
            fout[2 * i + 0] = __float22bfloat162_rn(make_float2(f.x, f.y));
            fout[2 * i + 1] = __float22bfloat162_rn(make_float2(f.z, f.w));
        }
    }
}

// ---- K2: block-local exclusive scan of cnt (1024 chunks) -> cursor,
//      block totals -> bsum. Cross-block add-back deferred to consumers
//      (64-entry redundant wave scan, free).
__global__ __launch_bounds__(1024) void k2_scan(const int* __restrict__ cnt,
                                                int* __restrict__ cursor,
                                                int* __restrict__ bsum) {
    __shared__ int s[1024];
    int tid = threadIdx.x;
    int j = blockIdx.x * 1024 + tid;
    int v = cnt[j];
    s[tid] = v;
    __syncthreads();
    for (int off = 1; off < 1024; off <<= 1) {
        int t = (tid >= off) ? s[tid - off] : 0;
        __syncthreads();
        s[tid] += t;
        __syncthreads();
    }
    cursor[j] = s[tid] - v;
    if (tid == 1023) bsum[blockIdx.x] = s[1023];
}

// wave-0 redundant exclusive scan of bsum[0..nblk) into sb[64]
__device__ inline void scan_bsum(const int* __restrict__ bsum, int nblk,
                                 int* sb, int tid) {
    if (tid < 64) {
        int v0 = (tid < nblk) ? bsum[tid] : 0;
        int v = v0;
        for (int off = 1; off < 64; off <<= 1) {
            int t = __shfl_up(v, off, 64);
            if (tid >= off) v += t;
        }
        sb[tid] = v - v0;
    }
}

// ---- K3: scatter edges to fully dst-sorted positions.
//      pos = sb[d>>10] + cursor[d]++ (global atomic, low contention).
__global__ __launch_bounds__(1024) void k3_scatter(
        const int* __restrict__ src, const int* __restrict__ dst,
        const float* __restrict__ vals, int E, int nblk,
        const int* __restrict__ bsum, int* __restrict__ cursor,
        int2* __restrict__ spack) {
    __shared__ int sb[MAXBLK];
    int tid = threadIdx.x;
    scan_bsum(bsum, nblk, sb, tid);
    __syncthreads();
    int idx = blockIdx.x * 1024 + tid;
    int stride = gridDim.x * 1024;
    for (int i = idx; i < E; i += stride) {
        int d = dst[i];
        int pos = sb[d >> 10] + atomicAdd(&cursor[d], 1);
        spack[pos] = make_int2(src[i], __float_as_int(vals[i]));
    }
}

// ---- K45: pure gather. One wave per node (wave-strided), no LDS staging,
//      no barriers, no sort. Clamped predicated groups-of-8 so remainder
//      edges issue 8 parallel loads instead of serial singles.
__global__ __launch_bounds__(1024) void k45_gather(
        const int* __restrict__ cnt, const int* __restrict__ cursor,
        const int* __restrict__ bsum, int nblk,
        const int2* __restrict__ spack, const __hip_bfloat162* __restrict__ feat,
        const float2* __restrict__ bias2, float2* __restrict__ out2, int N) {
    __shared__ int sb[MAXBLK];
    int tid = threadIdx.x;
    scan_bsum(bsum, nblk, sb, tid);
    __syncthreads();
    int lane = tid & 63;
    int w = blockIdx.x * (blockDim.x >> 6) + (tid >> 6);
    int nw = gridDim.x * (blockDim.x >> 6);
    float2 bv = bias2[lane];
    for (int n = w; n < N; n += nw) {
        int c = cnt[n];
        int endl = cursor[n];                  // local excl base + c (post-k3)
        int start = sb[n >> 10] + endl - c;
        int fin = start + c;
        float2 acc0 = bv;
        float2 acc1 = make_float2(0.f, 0.f);
        for (int g = 0; g < c; g += 8) {
            int2 p[8];
            __hip_bfloat162 h[8];
#pragma unroll
            for (int j = 0; j < 8; j++) {
                int ei = start + g + j;
                p[j] = spack[min(ei, fin - 1)];
            }
#pragma unroll
            for (int j = 0; j < 8; j++)
                h[j] = feat[(size_t)(unsigned)p[j].x * 64 + lane];
#pragma unroll
            for (int j = 0; j < 8; j++) {
                float v = (start + g + j < fin) ? __int_as_float(p[j].y) : 0.f;
                float2 f = __bfloat1622float2(h[j]);
                if (j & 1) { acc1.x += v * f.x; acc1.y += v * f.y; }
                else       { acc0.x += v * f.x; acc0.y += v * f.y; }
            }
        }
        acc0.x += acc1.x; acc0.y += acc1.y;
        out2[(size_t)n * 64 + lane] = acc0;
    }
}

// ---------- fallback atomic path ----------

__global__ void init_bias_kernel(float4* __restrict__ out,
                                 const float4* __restrict__ bias, int n4) {
    int i = blockIdx.x * blockDim.x + threadIdx.x;
    if (i < n4) out[i] = bias[i & (D4 - 1)];
}

__global__ void spmm_edge_kernel(const int* __restrict__ src,
                                 const int* __restrict__ dst,
                                 const float* __restrict__ vals,
                                 const float4* __restrict__ feat,
                                 float* __restrict__ out, int n_edges) {
    int tid = blockIdx.x * blockDim.x + threadIdx.x;
    int e = tid >> 5;
    int lane = tid & 31;
    if (e >= n_edges) return;
    int s = src[e];
    int d = dst[e];
    float v = vals[e];
    float4 f = feat[(size_t)s * D4 + lane];
    float* o = out + (size_t)d * D_FEAT + lane * 4;
    atomicAdd(o + 0, v * f.x);
    atomicAdd(o + 1, v * f.y);
    atomicAdd(o + 2, v * f.z);
    atomicAdd(o + 3, v * f.w);
}

extern "C" void kernel_launch(void* const* d_in, const int* in_sizes, int n_in,
                              void* d_out, int out_size, void* d_ws, size_t ws_size,
                              hipStream_t stream) {
    const int* edge_index = (const int*)d_in[0];    // (2, E) int32
    const float* edge_vals = (const float*)d_in[1]; // (E,)
    const float* features  = (const float*)d_in[2]; // (N, 128)
    const float* bias      = (const float*)d_in[3]; // (128,)

    int E = in_sizes[1];
    int N = in_sizes[2] / D_FEAT;
    const int* src = edge_index;
    const int* dst = edge_index + E;
    float* out = (float*)d_out;

    int NPAD = ((N + 1023) / 1024) * 1024;
    int nblk = NPAD / 1024;
    int n4 = N * D_FEAT / 4;

    // ws: fb16 | spack | cnt[NPAD] | cursor[NPAD] | bsum[MAXBLK]
    size_t fb_bytes = (size_t)N * D_FEAT * 2;
    size_t sp_bytes = (size_t)E * 8;
    size_t needed = fb_bytes + sp_bytes + (size_t)NPAD * 8 + MAXBLK * 4;

    bool ok = (ws_size >= needed) && (N >= 1) && (N <= 65536) && (E >= 1) &&
              (in_sizes[3] == D_FEAT) && (nblk <= MAXBLK);

    if (ok) {
        char* wp = (char*)d_ws;
        __hip_bfloat162* fb16 = (__hip_bfloat162*)wp;  wp += fb_bytes;
        int2* spack = (int2*)wp;                       wp += sp_bytes;
        int* cnt    = (int*)wp;                        wp += (size_t)NPAD * 4;
        int* cursor = (int*)wp;                        wp += (size_t)NPAD * 4;
        int* bsum   = (int*)wp;

        hipMemsetAsync(cnt, 0, (size_t)NPAD * 4, stream);
        k1_hist_cvt<<<512, 256, 0, stream>>>(dst, E, cnt,
                                             (const float4*)features, fb16, n4);
        k2_scan<<<nblk, 1024, 0, stream>>>(cnt, cursor, bsum);
        k3_scatter<<<256, 1024, 0, stream>>>(src, dst, edge_vals, E, nblk,
                                             bsum, cursor, spack);
        k45_gather<<<256, 1024, 0, stream>>>(cnt, cursor, bsum, nblk,
                                             spack, fb16, (const float2*)bias,
                                             (float2*)out, N);
    } else {
        int no4 = out_size / 4;
        {
            int block = 256, grid = (no4 + block - 1) / block;
            init_bias_kernel<<<grid, block, 0, stream>>>((float4*)out,
                                                         (const float4*)bias, no4);
        }
        {
            int block = 256;
            long long total = (long long)E * 32;
            int grid = (int)((total + block - 1) / block);
            spmm_edge_kernel<<<grid, block, 0, stream>>>(src, dst, edge_vals,
                                                         (const float4*)features,
                                                         out, E);
        }
    }
}

// Round 4
// 146.002 us; speedup vs baseline: 1.5475x; 1.5475x over previous
//
#include <hip/hip_runtime.h>
#include <hip/hip_bf16.h>

#define D_FEAT 128
#define D4 (D_FEAT / 4)
#define BKT_SHIFT 7            // 128 nodes per bucket
#define BKT_NODES 128
#define NCHUNK 256             // edge chunks (counting-sort columns)
#define MAXBKT 512
#define MAXBSUM 128            // max scan blocks (Mpad/1024)
#define CAP 3072               // LDS sorted-edge capacity per bucket

// ---- K1: per-chunk LDS histogram over buckets -> M[bkt*NCHUNK+chunk];
//      blocks >= NCHUNK convert fp32 features -> bf16 table.
__global__ __launch_bounds__(256) void k1_hist_cvt(
        const int* __restrict__ dst, int E, int chunk, int nbkt,
        int* __restrict__ M, int Mpad,
        const float4* __restrict__ fin, __hip_bfloat162* __restrict__ fout,
        int n4) {
    int c = blockIdx.x;
    int tid = threadIdx.x;
    if (c < NCHUNK) {
        __shared__ int hist[MAXBKT];
        for (int i = tid; i < nbkt; i += 256) hist[i] = 0;
        __syncthreads();
        int lo = c * chunk;
        int hi = min(lo + chunk, E);
        for (int i = lo + tid; i < hi; i += 256)
            atomicAdd(&hist[dst[i] >> BKT_SHIFT], 1);
        __syncthreads();
        for (int i = tid; i < nbkt; i += 256)
            M[i * NCHUNK + c] = hist[i];
        if (c == 0) {  // zero scan padding
            for (int i = nbkt * NCHUNK + tid; i < Mpad; i += 256) M[i] = 0;
        }
    } else {
        int nb = gridDim.x - NCHUNK;
        int idx = (c - NCHUNK) * 256 + tid;
        int stride = nb * 256;
        for (int i = idx; i < n4; i += stride) {
            float4 f = fin[i];
            fout[2 * i + 0] = __float22bfloat162_rn(make_float2(f.x, f.y));
            fout[2 * i + 1] = __float22bfloat162_rn(make_float2(f.z, f.w));
        }
    }
}

// ---- K2a: block-local exclusive scan of 1024 contiguous M entries (in place),
//      block total -> bsum[blk]. Cross-block add-back deferred to consumers
//      (tiny redundant in-block scan of bsum -- no k2b kernel).
__global__ __launch_bounds__(1024) void k2a_scan(int* __restrict__ M,
                                                 int* __restrict__ bsum) {
    __shared__ int s[1024];
    int tid = threadIdx.x;
    int j = blockIdx.x * 1024 + tid;
    int v = M[j];
    s[tid] = v;
    __syncthreads();
    for (int off = 1; off < 1024; off <<= 1) {
        int t = (tid >= off) ? s[tid - off] : 0;
        __syncthreads();
        s[tid] += t;
        __syncthreads();
    }
    M[j] = s[tid] - v;
    if (tid == 1023) bsum[blockIdx.x] = s[1023];
}

// redundant in-block exclusive scan of bsum[0..nblk) into sbs[MAXBSUM].
// All threads must reach the barriers; tid < MAXBSUM participate.
__device__ inline void scan_bsum_lds(const int* __restrict__ bsum, int nblk,
                                     int* sbs, int tid) {
    int v = 0;
    if (tid < MAXBSUM) {
        v = (tid < nblk) ? bsum[tid] : 0;
        sbs[tid] = v;
    }
    __syncthreads();
    for (int off = 1; off < MAXBSUM; off <<= 1) {
        int t = (tid < MAXBSUM && tid >= off) ? sbs[tid - off] : 0;
        __syncthreads();
        if (tid < MAXBSUM) sbs[tid] += t;
        __syncthreads();
    }
    if (tid < MAXBSUM) sbs[tid] -= v;   // exclusive
    __syncthreads();
}

// ---- K3: partition. Block c re-reads its chunk; LDS cursors seeded from the
//      scanned matrix + in-block bsum scan; writes land in ~one-line (~64B)
//      contiguous runs.
__global__ __launch_bounds__(512) void k3_partition(
        const int* __restrict__ src, const int* __restrict__ dst,
        const float* __restrict__ vals, int E, int chunk, int nbkt, int nblk,
        const int* __restrict__ M, const int* __restrict__ bsum,
        int2* __restrict__ spackA) {
    __shared__ int sbs[MAXBSUM];
    __shared__ int lcur[MAXBKT];
    int c = blockIdx.x;
    int tid = threadIdx.x;
    scan_bsum_lds(bsum, nblk, sbs, tid);
    for (int i = tid; i < nbkt; i += 512) {
        int j = i * NCHUNK + c;
        lcur[i] = M[j] + sbs[j >> 10];
    }
    __syncthreads();
    int lo = c * chunk;
    int hi = min(lo + chunk, E);
    for (int i = lo + tid; i < hi; i += 512) {
        int d = dst[i];
        int s = src[i];
        float v = vals[i];
        int pos = atomicAdd(&lcur[d >> BKT_SHIFT], 1);
        spackA[pos] = make_int2((s & 0xFFFF) | ((d & (BKT_NODES - 1)) << 16),
                                __float_as_int(v));
    }
}

// ---- K45: per-bucket counting sort INTO LDS + gather from LDS.
//      Overflow (cnt > CAP) falls back to global spackB for that bucket.
//      All degree remainders handled as clamped predicated groups-of-8
//      (8 parallel loads instead of up to 7 serial-latency singles).
__global__ __launch_bounds__(1024) void k45_sort_gather(
        const int* __restrict__ M, const int* __restrict__ bsum, int nblk,
        const int2* __restrict__ spackA, int2* __restrict__ spackB,
        const __hip_bfloat162* __restrict__ feat,
        const float2* __restrict__ bias2, float2* __restrict__ out2,
        int N, int nbkt) {
    __shared__ int sbs[MAXBSUM];
    __shared__ int hist[BKT_NODES];
    __shared__ int sbuf[BKT_NODES];   // inclusive scan (kept for gather)
    __shared__ int lcur[BKT_NODES];
    __shared__ int2 ls[CAP];
    int b = blockIdx.x;
    int tid = threadIdx.x;
    scan_bsum_lds(bsum, nblk, sbs, tid);
    int j0 = b * NCHUNK;
    int j1 = (b + 1) * NCHUNK;
    int base = M[j0] + sbs[j0 >> 10];
    int end  = M[j1] + sbs[j1 >> 10];
    int cnt = end - base;
    bool inlds = (cnt <= CAP);

    if (tid < BKT_NODES) hist[tid] = 0;
    __syncthreads();
    for (int i = tid; i < cnt; i += 1024)
        atomicAdd(&hist[(spackA[base + i].x >> 16) & (BKT_NODES - 1)], 1);
    __syncthreads();
    if (tid < BKT_NODES) sbuf[tid] = hist[tid];
    __syncthreads();
    for (int off = 1; off < BKT_NODES; off <<= 1) {
        int t = (tid < BKT_NODES && tid >= off) ? sbuf[tid - off] : 0;
        __syncthreads();
        if (tid < BKT_NODES) sbuf[tid] += t;
        __syncthreads();
    }
    if (tid < BKT_NODES) lcur[tid] = sbuf[tid] - hist[tid];
    __syncthreads();
    for (int i = tid; i < cnt; i += 1024) {
        int2 r = spackA[base + i];
        int p = atomicAdd(&lcur[(r.x >> 16) & (BKT_NODES - 1)], 1);
        if (inlds) ls[p] = r;
        else       spackB[base + p] = r;
    }
    __syncthreads();

    int wave = tid >> 6, lane = tid & 63;
    float2 bv = bias2[lane];
    for (int n = wave; n < BKT_NODES; n += 16) {
        int node = (b << BKT_SHIFT) + n;
        if (node >= N) break;
        int lbeg = sbuf[n] - hist[n];
        int lend = sbuf[n];
        float2 acc0 = bv;
        float2 acc1 = make_float2(0.f, 0.f);
        if (inlds) {
            for (int e0 = lbeg; e0 < lend; e0 += 8) {
                int2 p[8];
                __hip_bfloat162 h[8];
#pragma unroll
                for (int j = 0; j < 8; j++) p[j] = ls[min(e0 + j, lend - 1)];
#pragma unroll
                for (int j = 0; j < 8; j++)
                    h[j] = feat[(size_t)(p[j].x & 0xFFFF) * 64 + lane];
#pragma unroll
                for (int j = 0; j < 8; j++) {
                    float v = (e0 + j < lend) ? __int_as_float(p[j].y) : 0.f;
                    float2 f = __bfloat1622float2(h[j]);
                    if (j & 1) { acc1.x += v * f.x; acc1.y += v * f.y; }
                    else       { acc0.x += v * f.x; acc0.y += v * f.y; }
                }
            }
        } else {
            for (int e0 = lbeg; e0 < lend; e0 += 8) {
                int2 p[8];
                __hip_bfloat162 h[8];
#pragma unroll
                for (int j = 0; j < 8; j++)
                    p[j] = spackB[base + min(e0 + j, lend - 1)];
#pragma unroll
                for (int j = 0; j < 8; j++)
                    h[j] = feat[(size_t)(p[j].x & 0xFFFF) * 64 + lane];
#pragma unroll
                for (int j = 0; j < 8; j++) {
                    float v = (e0 + j < lend) ? __int_as_float(p[j].y) : 0.f;
                    float2 f = __bfloat1622float2(h[j]);
                    if (j & 1) { acc1.x += v * f.x; acc1.y += v * f.y; }
                    else       { acc0.x += v * f.x; acc0.y += v * f.y; }
                }
            }
        }
        acc0.x += acc1.x; acc0.y += acc1.y;
        out2[(size_t)node * 64 + lane] = acc0;
    }
}

// ---------- fallback atomic path ----------

__global__ void init_bias_kernel(float4* __restrict__ out,
                                 const float4* __restrict__ bias, int n4) {
    int i = blockIdx.x * blockDim.x + threadIdx.x;
    if (i < n4) out[i] = bias[i & (D4 - 1)];
}

__global__ void spmm_edge_kernel(const int* __restrict__ src,
                                 const int* __restrict__ dst,
                                 const float* __restrict__ vals,
                                 const float4* __restrict__ feat,
                                 float* __restrict__ out, int n_edges) {
    int tid = blockIdx.x * blockDim.x + threadIdx.x;
    int e = tid >> 5;
    int lane = tid & 31;
    if (e >= n_edges) return;
    int s = src[e];
    int d = dst[e];
    float v = vals[e];
    float4 f = feat[(size_t)s * D4 + lane];
    float* o = out + (size_t)d * D_FEAT + lane * 4;
    atomicAdd(o + 0, v * f.x);
    atomicAdd(o + 1, v * f.y);
    atomicAdd(o + 2, v * f.z);
    atomicAdd(o + 3, v * f.w);
}

extern "C" void kernel_launch(void* const* d_in, const int* in_sizes, int n_in,
                              void* d_out, int out_size, void* d_ws, size_t ws_size,
                              hipStream_t stream) {
    const int* edge_index = (const int*)d_in[0];    // (2, E) int32
    const float* edge_vals = (const float*)d_in[1]; // (E,)
    const float* features  = (const float*)d_in[2]; // (N, 128)
    const float* bias      = (const float*)d_in[3]; // (128,)

    int E = in_sizes[1];
    int N = in_sizes[2] / D_FEAT;
    const int* src = edge_index;
    const int* dst = edge_index + E;
    float* out = (float*)d_out;

    int nbkt = (N + BKT_NODES - 1) >> BKT_SHIFT;
    int n4 = N * D_FEAT / 4;
    int chunk = (E + NCHUNK - 1) / NCHUNK;
    int Mpad = ((nbkt * NCHUNK + 1 + 1023) / 1024) * 1024;  // >= nbkt*NCHUNK+1
    int nblk2 = Mpad / 1024;

    // ws: fb16 | spackA | spackB | M[Mpad] | bsum[nblk2]
    size_t fb_bytes = (size_t)N * D_FEAT * 2;
    size_t sp_bytes = (size_t)E * 8;
    size_t needed = fb_bytes + 2 * sp_bytes +
                    ((size_t)Mpad + nblk2) * 4;

    bool ok = (ws_size >= needed) && (N >= 1) && (N <= 65536) && (E >= 1) &&
              (in_sizes[3] == D_FEAT) && (nbkt <= MAXBKT) && (nblk2 <= MAXBSUM);

    if (ok) {
        char* wp = (char*)d_ws;
        __hip_bfloat162* fb16 = (__hip_bfloat162*)wp;  wp += fb_bytes;
        int2* spackA = (int2*)wp;                      wp += sp_bytes;
        int2* spackB = (int2*)wp;                      wp += sp_bytes;
        int* M       = (int*)wp;                       wp += (size_t)Mpad * 4;
        int* bsum    = (int*)wp;

        k1_hist_cvt<<<NCHUNK + 256, 256, 0, stream>>>(dst, E, chunk, nbkt,
                                                      M, Mpad,
                                                      (const float4*)features,
                                                      fb16, n4);
        k2a_scan<<<nblk2, 1024, 0, stream>>>(M, bsum);
        k3_partition<<<NCHUNK, 512, 0, stream>>>(src, dst, edge_vals, E, chunk,
                                                 nbkt, nblk2, M, bsum, spackA);
        k45_sort_gather<<<nbkt, 1024, 0, stream>>>(M, bsum, nblk2,
                                                   spackA, spackB,
                                                   fb16, (const float2*)bias,
                                                   (float2*)out, N, nbkt);
    } else {
        int no4 = out_size / 4;
        {
            int block = 256, grid = (no4 + block - 1) / block;
            init_bias_kernel<<<grid, block, 0, stream>>>((float4*)out,
                                                         (const float4*)bias, no4);
        }
        {
            int block = 256;
            long long total = (long long)E * 32;
            int grid = (int)((total + block - 1) / block);
            spmm_edge_kernel<<<grid, block, 0, stream>>>(src, dst, edge_vals,
                                                         (const float4*)features,
                                                         out, E);
        }
    }
}

// Round 5
// 144.081 us; speedup vs baseline: 1.5681x; 1.0133x over previous
//
#include <hip/hip_runtime.h>
#include <hip/hip_bf16.h>

#define D_FEAT 128
#define D4 (D_FEAT / 4)
#define BKT_SHIFT 7            // 128 nodes per bucket
#define BKT_NODES 128
#define NCHUNK 256             // edge chunks (counting-sort columns)
#define MAXBKT 512
#define MAXBSUM 128            // max scan blocks (Mpad/1024)
#define CAP 3072               // LDS sorted-edge capacity per bucket

__device__ inline unsigned pack_bf2(float lo, float hi) {
    __hip_bfloat162 h = __float22bfloat162_rn(make_float2(lo, hi));
    unsigned u;
    __builtin_memcpy(&u, &h, 4);
    return u;
}

// ---- K1: per-chunk LDS histogram over buckets -> M[bkt*NCHUNK+chunk];
//      blocks >= NCHUNK convert fp32 features -> bf16 table (8B stores).
__global__ __launch_bounds__(256) void k1_hist_cvt(
        const int* __restrict__ dst, int E, int chunk, int nbkt,
        int* __restrict__ M, int Mpad,
        const float4* __restrict__ fin, uint2* __restrict__ fout,
        int n4) {
    int c = blockIdx.x;
    int tid = threadIdx.x;
    if (c < NCHUNK) {
        __shared__ int hist[MAXBKT];
        for (int i = tid; i < nbkt; i += 256) hist[i] = 0;
        __syncthreads();
        int lo = c * chunk;
        int hi = min(lo + chunk, E);
        for (int i = lo + tid; i < hi; i += 256)
            atomicAdd(&hist[dst[i] >> BKT_SHIFT], 1);
        __syncthreads();
        for (int i = tid; i < nbkt; i += 256)
            M[i * NCHUNK + c] = hist[i];
        if (c == 0) {  // zero scan padding
            for (int i = nbkt * NCHUNK + tid; i < Mpad; i += 256) M[i] = 0;
        }
    } else {
        int nb = gridDim.x - NCHUNK;
        int idx = (c - NCHUNK) * 256 + tid;
        int stride = nb * 256;
        for (int i = idx; i < n4; i += stride) {
            float4 f = fin[i];
            uint2 o;
            o.x = pack_bf2(f.x, f.y);
            o.y = pack_bf2(f.z, f.w);
            fout[i] = o;
        }
    }
}

// ---- K2a: block-local exclusive scan of 1024 contiguous M entries (in place),
//      block total -> bsum[blk]. Add-back deferred to consumers.
__global__ __launch_bounds__(1024) void k2a_scan(int* __restrict__ M,
                                                 int* __restrict__ bsum) {
    __shared__ int s[1024];
    int tid = threadIdx.x;
    int j = blockIdx.x * 1024 + tid;
    int v = M[j];
    s[tid] = v;
    __syncthreads();
    for (int off = 1; off < 1024; off <<= 1) {
        int t = (tid >= off) ? s[tid - off] : 0;
        __syncthreads();
        s[tid] += t;
        __syncthreads();
    }
    M[j] = s[tid] - v;
    if (tid == 1023) bsum[blockIdx.x] = s[1023];
}

// single-wave redundant exclusive scan of bsum[0..nblk) into sbs[MAXBSUM].
// 2 entries per lane, shfl inclusive scan. One barrier after.
__device__ inline void scan_bsum_wave(const int* __restrict__ bsum, int nblk,
                                      int* sbs, int tid) {
    if (tid < 64) {
        int i0 = 2 * tid, i1 = 2 * tid + 1;
        int h0 = (i0 < nblk) ? bsum[i0] : 0;
        int h1 = (i1 < nblk) ? bsum[i1] : 0;
        int s = h0 + h1;
        int v = s;
        for (int off = 1; off < 64; off <<= 1) {
            int t = __shfl_up(v, off, 64);
            if (tid >= off) v += t;
        }
        sbs[i0] = v - s;          // exclusive
        sbs[i1] = v - s + h0;
    }
    __syncthreads();
}

// ---- K3: partition. Block c re-reads its chunk; LDS cursors seeded from the
//      scanned matrix + in-block bsum scan; writes land in ~one-line (~64B)
//      contiguous runs.
__global__ __launch_bounds__(512) void k3_partition(
        const int* __restrict__ src, const int* __restrict__ dst,
        const float* __restrict__ vals, int E, int chunk, int nbkt, int nblk,
        const int* __restrict__ M, const int* __restrict__ bsum,
        int2* __restrict__ spackA) {
    __shared__ int sbs[MAXBSUM];
    __shared__ int lcur[MAXBKT];
    int c = blockIdx.x;
    int tid = threadIdx.x;
    scan_bsum_wave(bsum, nblk, sbs, tid);
    for (int i = tid; i < nbkt; i += 512) {
        int j = i * NCHUNK + c;
        lcur[i] = M[j] + sbs[j >> 10];
    }
    __syncthreads();
    int lo = c * chunk;
    int hi = min(lo + chunk, E);
    for (int i = lo + tid; i < hi; i += 512) {
        int d = dst[i];
        int s = src[i];
        float v = vals[i];
        int pos = atomicAdd(&lcur[d >> BKT_SHIFT], 1);
        spackA[pos] = make_int2((s & 0xFFFF) | ((d & (BKT_NODES - 1)) << 16),
                                __float_as_int(v));
    }
}

// ---- K45: per-bucket counting sort INTO LDS + paired gather.
//      Gather: lanes 0-31 take even edges, 32-63 odd edges of the same node;
//      each lane loads uint2 (4 bf16 feats, 8B). Cross-half reduce via
//      __shfl_xor(.,32), 16B store from lanes 0-31.
//      Overflow (cnt > CAP) falls back to global spackB for that bucket.
__global__ __launch_bounds__(1024) void k45_sort_gather(
        const int* __restrict__ M, const int* __restrict__ bsum, int nblk,
        const int2* __restrict__ spackA, int2* __restrict__ spackB,
        const uint2* __restrict__ feat2,
        const float4* __restrict__ bias4, float4* __restrict__ out4,
        int N, int nbkt) {
    __shared__ int sbs[MAXBSUM];
    __shared__ int hist[BKT_NODES];
    __shared__ int sbuf[BKT_NODES];   // inclusive scan (kept for gather)
    __shared__ int lcur[BKT_NODES];
    __shared__ int2 ls[CAP];
    int b = blockIdx.x;
    int tid = threadIdx.x;
    scan_bsum_wave(bsum, nblk, sbs, tid);
    int j0 = b * NCHUNK;
    int j1 = (b + 1) * NCHUNK;
    int base = M[j0] + sbs[j0 >> 10];
    int end  = M[j1] + sbs[j1 >> 10];
    int cnt = end - base;
    bool inlds = (cnt <= CAP);

    if (tid < BKT_NODES) hist[tid] = 0;
    __syncthreads();
    for (int i = tid; i < cnt; i += 1024)
        atomicAdd(&hist[(spackA[base + i].x >> 16) & (BKT_NODES - 1)], 1);
    __syncthreads();
    // single-wave scan of the 128-entry histogram (2/lane, shfl)
    if (tid < 64) {
        int h0 = hist[2 * tid], h1 = hist[2 * tid + 1];
        int s = h0 + h1;
        int v = s;
        for (int off = 1; off < 64; off <<= 1) {
            int t = __shfl_up(v, off, 64);
            if (tid >= off) v += t;
        }
        sbuf[2 * tid]     = v - h1;   // inclusive at 2l
        sbuf[2 * tid + 1] = v;        // inclusive at 2l+1
        lcur[2 * tid]     = v - s;    // exclusive
        lcur[2 * tid + 1] = v - h1;
    }
    __syncthreads();
    for (int i = tid; i < cnt; i += 1024) {
        int2 r = spackA[base + i];
        int p = atomicAdd(&lcur[(r.x >> 16) & (BKT_NODES - 1)], 1);
        if (inlds) ls[p] = r;
        else       spackB[base + p] = r;
    }
    __syncthreads();

    int wave = tid >> 6, lane = tid & 63;
    int half = lane >> 5;           // 0: even edges, 1: odd edges
    int hl   = lane & 31;           // feature group: feats 4hl..4hl+3
    float4 bv = bias4[hl];
    for (int n = wave; n < BKT_NODES; n += 16) {
        int node = (b << BKT_SHIFT) + n;
        if (node >= N) break;
        int lend = sbuf[n];
        int lbeg = lend - hist[n];
        float4 acc0 = make_float4(0.f, 0.f, 0.f, 0.f);
        float4 acc1 = make_float4(0.f, 0.f, 0.f, 0.f);
        if (inlds) {
            for (int e0 = lbeg; e0 < lend; e0 += 16) {
                int2 p[8];
                uint2 h[8];
#pragma unroll
                for (int j = 0; j < 8; j++)
                    p[j] = ls[min(e0 + 2 * j + half, lend - 1)];
#pragma unroll
                for (int j = 0; j < 8; j++)
                    h[j] = feat2[(size_t)(p[j].x & 0xFFFF) * 32 + hl];
#pragma unroll
                for (int j = 0; j < 8; j++) {
                    float v = (e0 + 2 * j + half < lend) ? __int_as_float(p[j].y) : 0.f;
                    __hip_bfloat162 blo, bhi;
                    __builtin_memcpy(&blo, &h[j].x, 4);
                    __builtin_memcpy(&bhi, &h[j].y, 4);
                    float2 f01 = __bfloat1622float2(blo);
                    float2 f23 = __bfloat1622float2(bhi);
                    if (j & 1) {
                        acc1.x += v * f01.x; acc1.y += v * f01.y;
                        acc1.z += v * f23.x; acc1.w += v * f23.y;
                    } else {
                        acc0.x += v * f01.x; acc0.y += v * f01.y;
                        acc0.z += v * f23.x; acc0.w += v * f23.y;
                    }
                }
            }
        } else {
            for (int e0 = lbeg; e0 < lend; e0 += 16) {
                int2 p[8];
                uint2 h[8];
#pragma unroll
                for (int j = 0; j < 8; j++)
                    p[j] = spackB[base + min(e0 + 2 * j + half, lend - 1)];
#pragma unroll
                for (int j = 0; j < 8; j++)
                    h[j] = feat2[(size_t)(p[j].x & 0xFFFF) * 32 + hl];
#pragma unroll
                for (int j = 0; j < 8; j++) {
                    float v = (e0 + 2 * j + half < lend) ? __int_as_float(p[j].y) : 0.f;
                    __hip_bfloat162 blo, bhi;
                    __builtin_memcpy(&blo, &h[j].x, 4);
                    __builtin_memcpy(&bhi, &h[j].y, 4);
                    float2 f01 = __bfloat1622float2(blo);
                    float2 f23 = __bfloat1622float2(bhi);
                    if (j & 1) {
                        acc1.x += v * f01.x; acc1.y += v * f01.y;
                        acc1.z += v * f23.x; acc1.w += v * f23.y;
                    } else {
                        acc0.x += v * f01.x; acc0.y += v * f01.y;
                        acc0.z += v * f23.x; acc0.w += v * f23.y;
                    }
                }
            }
        }
        acc0.x += acc1.x; acc0.y += acc1.y;
        acc0.z += acc1.z; acc0.w += acc1.w;
        // cross-half reduce (even-edge half + odd-edge half)
        acc0.x += __shfl_xor(acc0.x, 32);
        acc0.y += __shfl_xor(acc0.y, 32);
        acc0.z += __shfl_xor(acc0.z, 32);
        acc0.w += __shfl_xor(acc0.w, 32);
        if (half == 0) {
            out4[(size_t)node * 32 + hl] =
                make_float4(acc0.x + bv.x, acc0.y + bv.y,
                            acc0.z + bv.z, acc0.w + bv.w);
        }
    }
}

// ---------- fallback atomic path ----------

__global__ void init_bias_kernel(float4* __restrict__ out,
                                 const float4* __restrict__ bias, int n4) {
    int i = blockIdx.x * blockDim.x + threadIdx.x;
    if (i < n4) out[i] = bias[i & (D4 - 1)];
}

__global__ void spmm_edge_kernel(const int* __restrict__ src,
                                 const int* __restrict__ dst,
                                 const float* __restrict__ vals,
                                 const float4* __restrict__ feat,
                                 float* __restrict__ out, int n_edges) {
    int tid = blockIdx.x * blockDim.x + threadIdx.x;
    int e = tid >> 5;
    int lane = tid & 31;
    if (e >= n_edges) return;
    int s = src[e];
    int d = dst[e];
    float v = vals[e];
    float4 f = feat[(size_t)s * D4 + lane];
    float* o = out + (size_t)d * D_FEAT + lane * 4;
    atomicAdd(o + 0, v * f.x);
    atomicAdd(o + 1, v * f.y);
    atomicAdd(o + 2, v * f.z);
    atomicAdd(o + 3, v * f.w);
}

extern "C" void kernel_launch(void* const* d_in, const int* in_sizes, int n_in,
                              void* d_out, int out_size, void* d_ws, size_t ws_size,
                              hipStream_t stream) {
    const int* edge_index = (const int*)d_in[0];    // (2, E) int32
    const float* edge_vals = (const float*)d_in[1]; // (E,)
    const float* features  = (const float*)d_in[2]; // (N, 128)
    const float* bias      = (const float*)d_in[3]; // (128,)

    int E = in_sizes[1];
    int N = in_sizes[2] / D_FEAT;
    const int* src = edge_index;
    const int* dst = edge_index + E;
    float* out = (float*)d_out;

    int nbkt = (N + BKT_NODES - 1) >> BKT_SHIFT;
    int n4 = N * D_FEAT / 4;
    int chunk = (E + NCHUNK - 1) / NCHUNK;
    int Mpad = ((nbkt * NCHUNK + 1 + 1023) / 1024) * 1024;  // >= nbkt*NCHUNK+1
    int nblk2 = Mpad / 1024;

    // ws: fb16 | spackA | spackB | M[Mpad] | bsum[nblk2]
    size_t fb_bytes = (size_t)N * D_FEAT * 2;
    size_t sp_bytes = (size_t)E * 8;
    size_t needed = fb_bytes + 2 * sp_bytes +
                    ((size_t)Mpad + nblk2) * 4;

    bool ok = (ws_size >= needed) && (N >= 1) && (N <= 65536) && (E >= 1) &&
              (in_sizes[3] == D_FEAT) && (nbkt <= MAXBKT) && (nblk2 <= MAXBSUM);

    if (ok) {
        char* wp = (char*)d_ws;
        uint2* fb16 = (uint2*)wp;                      wp += fb_bytes;
        int2* spackA = (int2*)wp;                      wp += sp_bytes;
        int2* spackB = (int2*)wp;                      wp += sp_bytes;
        int* M       = (int*)wp;                       wp += (size_t)Mpad * 4;
        int* bsum    = (int*)wp;

        k1_hist_cvt<<<NCHUNK + 256, 256, 0, stream>>>(dst, E, chunk, nbkt,
                                                      M, Mpad,
                                                      (const float4*)features,
                                                      fb16, n4);
        k2a_scan<<<nblk2, 1024, 0, stream>>>(M, bsum);
        k3_partition<<<NCHUNK, 512, 0, stream>>>(src, dst, edge_vals, E, chunk,
                                                 nbkt, nblk2, M, bsum, spackA);
        k45_sort_gather<<<nbkt, 1024, 0, stream>>>(M, bsum, nblk2,
                                                   spackA, spackB,
                                                   (const uint2*)fb16,
                                                   (const float4*)bias,
                                                   (float4*)out, N, nbkt);
    } else {
        int no4 = out_size / 4;
        {
            int block = 256, grid = (no4 + block - 1) / block;
            init_bias_kernel<<<grid, block, 0, stream>>>((float4*)out,
                                                         (const float4*)bias, no4);
        }
        {
            int block = 256;
            long long total = (long long)E * 32;
            int grid = (int)((total + block - 1) / block);
            spmm_edge_kernel<<<grid, block, 0, stream>>>(src, dst, edge_vals,
                                                         (const float4*)features,
                                                         out, E);
        }
    }
}

// Round 6
// 142.455 us; speedup vs baseline: 1.5860x; 1.0114x over previous
//
#include <hip/hip_runtime.h>
#include <hip/hip_bf16.h>
#include <hip/hip_cooperative_groups.h>

namespace cg = cooperative_groups;

#define D_FEAT 128
#define D4 (D_FEAT / 4)
#define BKT_SHIFT 7            // 128 nodes per bucket
#define BKT_NODES 128
#define NCHUNK 256             // edge chunks (counting-sort columns)
#define MAXBKT 512
#define MAXBSUM 128            // max scan blocks (Mpad/1024)
#define CAP 3072               // LDS sorted-edge capacity per bucket

__device__ inline unsigned pack_bf2(float lo, float hi) {
    __hip_bfloat162 h = __float22bfloat162_rn(make_float2(lo, hi));
    unsigned u;
    __builtin_memcpy(&u, &h, 4);
    return u;
}

// single-wave redundant exclusive scan of bsum[0..nblk) into sbs[MAXBSUM].
__device__ inline void scan_bsum_wave(const int* __restrict__ bsum, int nblk,
                                      int* sbs, int tid) {
    if (tid < 64) {
        int i0 = 2 * tid, i1 = 2 * tid + 1;
        int h0 = (i0 < nblk) ? bsum[i0] : 0;
        int h1 = (i1 < nblk) ? bsum[i1] : 0;
        int s = h0 + h1;
        int v = s;
        for (int off = 1; off < 64; off <<= 1) {
            int t = __shfl_up(v, off, 64);
            if (tid >= off) v += t;
        }
        sbs[i0] = v - s;          // exclusive
        sbs[i1] = v - s + h0;
    }
    __syncthreads();
}

// ================= fused cooperative pipeline =================
__global__ __launch_bounds__(1024) void fused_all(
        const int* __restrict__ src, const int* __restrict__ dst,
        const float* __restrict__ vals, int E, int chunk,
        int nbkt, int Mpad, int nblk2,
        int* __restrict__ M, int* __restrict__ bsum,
        int2* __restrict__ spackA, int2* __restrict__ spackB,
        const float4* __restrict__ fin4, uint2* __restrict__ fb16, int n4,
        const float4* __restrict__ bias4, float4* __restrict__ out4, int N) {
    cg::grid_group grid = cg::this_grid();
    __shared__ int sh_hist[MAXBKT];
    __shared__ int sh_scan[1024];
    __shared__ int sbs[MAXBSUM];
    __shared__ int lcur[MAXBKT];
    __shared__ int h4[BKT_NODES];
    __shared__ int sb4[BKT_NODES];
    __shared__ int lc4[BKT_NODES];
    __shared__ int2 ls[CAP];
    int b = blockIdx.x;
    int tid = threadIdx.x;
    int G = gridDim.x;

    // ---- phase 1: per-chunk bucket histogram + feature fp32->bf16 cvt
    for (int c = b; c < NCHUNK; c += G) {
        for (int i = tid; i < nbkt; i += 1024) sh_hist[i] = 0;
        __syncthreads();
        int lo = c * chunk;
        int hi = min(lo + chunk, E);
        for (int i = lo + tid; i < hi; i += 1024)
            atomicAdd(&sh_hist[dst[i] >> BKT_SHIFT], 1);
        __syncthreads();
        for (int i = tid; i < nbkt; i += 1024) M[i * NCHUNK + c] = sh_hist[i];
        __syncthreads();
    }
    {
        int g0 = b * 1024 + tid;
        for (int i = nbkt * NCHUNK + g0; i < Mpad; i += G * 1024) M[i] = 0;
        for (int i = g0; i < n4; i += G * 1024) {
            float4 f = fin4[i];
            uint2 o;
            o.x = pack_bf2(f.x, f.y);
            o.y = pack_bf2(f.z, f.w);
            fb16[i] = o;
        }
    }
    grid.sync();

    // ---- phase 2: block-local exclusive scans of M, totals -> bsum
    for (int blk = b; blk < nblk2; blk += G) {
        int j = blk * 1024 + tid;
        int v = M[j];
        sh_scan[tid] = v;
        __syncthreads();
        for (int off = 1; off < 1024; off <<= 1) {
            int t = (tid >= off) ? sh_scan[tid - off] : 0;
            __syncthreads();
            sh_scan[tid] += t;
            __syncthreads();
        }
        M[j] = sh_scan[tid] - v;
        if (tid == 1023) bsum[blk] = sh_scan[1023];
        __syncthreads();
    }
    grid.sync();

    // ---- phase 3: partition into bucket-contiguous spackA
    scan_bsum_wave(bsum, nblk2, sbs, tid);     // sbs reused by phase 4
    for (int c = b; c < NCHUNK; c += G) {
        for (int i = tid; i < nbkt; i += 1024) {
            int j = i * NCHUNK + c;
            lcur[i] = M[j] + sbs[j >> 10];
        }
        __syncthreads();
        int lo = c * chunk;
        int hi = min(lo + chunk, E);
        for (int i = lo + tid; i < hi; i += 1024) {
            int d = dst[i];
            int pos = atomicAdd(&lcur[d >> BKT_SHIFT], 1);
            spackA[pos] = make_int2((src[i] & 0xFFFF) |
                                    ((d & (BKT_NODES - 1)) << 16),
                                    __float_as_int(vals[i]));
        }
        __syncthreads();
    }
    grid.sync();

    // ---- phase 4: per-bucket counting sort into LDS + paired gather
    for (int bk = b; bk < nbkt; bk += G) {
        int j0 = bk * NCHUNK;
        int j1 = (bk + 1) * NCHUNK;
        int base = M[j0] + sbs[j0 >> 10];
        int end  = M[j1] + sbs[j1 >> 10];
        int cnt = end - base;
        bool inlds = (cnt <= CAP);

        if (tid < BKT_NODES) h4[tid] = 0;
        __syncthreads();
        for (int i = tid; i < cnt; i += 1024)
            atomicAdd(&h4[(spackA[base + i].x >> 16) & (BKT_NODES - 1)], 1);
        __syncthreads();
        if (tid < 64) {
            int h0 = h4[2 * tid], h1 = h4[2 * tid + 1];
            int s = h0 + h1;
            int v = s;
            for (int off = 1; off < 64; off <<= 1) {
                int t = __shfl_up(v, off, 64);
                if (tid >= off) v += t;
            }
            sb4[2 * tid]     = v - h1;
            sb4[2 * tid + 1] = v;
            lc4[2 * tid]     = v - s;
            lc4[2 * tid + 1] = v - h1;
        }
        __syncthreads();
        for (int i = tid; i < cnt; i += 1024) {
            int2 r = spackA[base + i];
            int p = atomicAdd(&lc4[(r.x >> 16) & (BKT_NODES - 1)], 1);
            if (inlds) ls[p] = r;
            else       spackB[base + p] = r;
        }
        __syncthreads();

        int wave = tid >> 6, lane = tid & 63;
        int half = lane >> 5;           // 0: even edges, 1: odd edges
        int hl   = lane & 31;           // feature group: feats 4hl..4hl+3
        float4 bv = bias4[hl];
        for (int n = wave; n < BKT_NODES; n += 16) {
            int node = (bk << BKT_SHIFT) + n;
            if (node >= N) break;
            int lend = sb4[n];
            int lbeg = lend - h4[n];
            float4 a0 = make_float4(0.f, 0.f, 0.f, 0.f);
            float4 a1 = make_float4(0.f, 0.f, 0.f, 0.f);
            if (inlds) {
                for (int e0 = lbeg; e0 < lend; e0 += 16) {
                    int2 p[8];
                    uint2 h[8];
#pragma unroll
                    for (int j = 0; j < 8; j++)
                        p[j] = ls[min(e0 + 2 * j + half, lend - 1)];
#pragma unroll
                    for (int j = 0; j < 8; j++)
                        h[j] = fb16[(size_t)(p[j].x & 0xFFFF) * 32 + hl];
#pragma unroll
                    for (int j = 0; j < 8; j++) {
                        float v = (e0 + 2 * j + half < lend) ?
                                  __int_as_float(p[j].y) : 0.f;
                        __hip_bfloat162 blo, bhi;
                        __builtin_memcpy(&blo, &h[j].x, 4);
                        __builtin_memcpy(&bhi, &h[j].y, 4);
                        float2 f01 = __bfloat1622float2(blo);
                        float2 f23 = __bfloat1622float2(bhi);
                        if (j & 1) {
                            a1.x += v * f01.x; a1.y += v * f01.y;
                            a1.z += v * f23.x; a1.w += v * f23.y;
                        } else {
                            a0.x += v * f01.x; a0.y += v * f01.y;
                            a0.z += v * f23.x; a0.w += v * f23.y;
                        }
                    }
                }
            } else {
                for (int e0 = lbeg; e0 < lend; e0 += 16) {
                    int2 p[8];
                    uint2 h[8];
#pragma unroll
                    for (int j = 0; j < 8; j++)
                        p[j] = spackB[base + min(e0 + 2 * j + half, lend - 1)];
#pragma unroll
                    for (int j = 0; j < 8; j++)
                        h[j] = fb16[(size_t)(p[j].x & 0xFFFF) * 32 + hl];
#pragma unroll
                    for (int j = 0; j < 8; j++) {
                        float v = (e0 + 2 * j + half < lend) ?
                                  __int_as_float(p[j].y) : 0.f;
                        __hip_bfloat162 blo, bhi;
                        __builtin_memcpy(&blo, &h[j].x, 4);
                        __builtin_memcpy(&bhi, &h[j].y, 4);
                        float2 f01 = __bfloat1622float2(blo);
                        float2 f23 = __bfloat1622float2(bhi);
                        if (j & 1) {
                            a1.x += v * f01.x; a1.y += v * f01.y;
                            a1.z += v * f23.x; a1.w += v * f23.y;
                        } else {
                            a0.x += v * f01.x; a0.y += v * f01.y;
                            a0.z += v * f23.x; a0.w += v * f23.y;
                        }
                    }
                }
            }
            a0.x += a1.x; a0.y += a1.y; a0.z += a1.z; a0.w += a1.w;
            a0.x += __shfl_xor(a0.x, 32);
            a0.y += __shfl_xor(a0.y, 32);
            a0.z += __shfl_xor(a0.z, 32);
            a0.w += __shfl_xor(a0.w, 32);
            if (half == 0) {
                out4[(size_t)node * 32 + hl] =
                    make_float4(a0.x + bv.x, a0.y + bv.y,
                                a0.z + bv.z, a0.w + bv.w);
            }
        }
        __syncthreads();
    }
}

// ================= 4-kernel fallback pipeline (round-5, proven) =================

__global__ __launch_bounds__(256) void k1_hist_cvt(
        const int* __restrict__ dst, int E, int chunk, int nbkt,
        int* __restrict__ M, int Mpad,
        const float4* __restrict__ fin, uint2* __restrict__ fout,
        int n4) {
    int c = blockIdx.x;
    int tid = threadIdx.x;
    if (c < NCHUNK) {
        __shared__ int hist[MAXBKT];
        for (int i = tid; i < nbkt; i += 256) hist[i] = 0;
        __syncthreads();
        int lo = c * chunk;
        int hi = min(lo + chunk, E);
        for (int i = lo + tid; i < hi; i += 256)
            atomicAdd(&hist[dst[i] >> BKT_SHIFT], 1);
        __syncthreads();
        for (int i = tid; i < nbkt; i += 256)
            M[i * NCHUNK + c] = hist[i];
        if (c == 0) {
            for (int i = nbkt * NCHUNK + tid; i < Mpad; i += 256) M[i] = 0;
        }
    } else {
        int nb = gridDim.x - NCHUNK;
        int idx = (c - NCHUNK) * 256 + tid;
        int stride = nb * 256;
        for (int i = idx; i < n4; i += stride) {
            float4 f = fin[i];
            uint2 o;
            o.x = pack_bf2(f.x, f.y);
            o.y = pack_bf2(f.z, f.w);
            fout[i] = o;
        }
    }
}

__global__ __launch_bounds__(1024) void k2a_scan(int* __restrict__ M,
                                                 int* __restrict__ bsum) {
    __shared__ int s[1024];
    int tid = threadIdx.x;
    int j = blockIdx.x * 1024 + tid;
    int v = M[j];
    s[tid] = v;
    __syncthreads();
    for (int off = 1; off < 1024; off <<= 1) {
        int t = (tid >= off) ? s[tid - off] : 0;
        __syncthreads();
        s[tid] += t;
        __syncthreads();
    }
    M[j] = s[tid] - v;
    if (tid == 1023) bsum[blockIdx.x] = s[1023];
}

__global__ __launch_bounds__(512) void k3_partition(
        const int* __restrict__ src, const int* __restrict__ dst,
        const float* __restrict__ vals, int E, int chunk, int nbkt, int nblk,
        const int* __restrict__ M, const int* __restrict__ bsum,
        int2* __restrict__ spackA) {
    __shared__ int sbs[MAXBSUM];
    __shared__ int lcur[MAXBKT];
    int c = blockIdx.x;
    int tid = threadIdx.x;
    scan_bsum_wave(bsum, nblk, sbs, tid);
    for (int i = tid; i < nbkt; i += 512) {
        int j = i * NCHUNK + c;
        lcur[i] = M[j] + sbs[j >> 10];
    }
    __syncthreads();
    int lo = c * chunk;
    int hi = min(lo + chunk, E);
    for (int i = lo + tid; i < hi; i += 512) {
        int d = dst[i];
        int pos = atomicAdd(&lcur[d >> BKT_SHIFT], 1);
        spackA[pos] = make_int2((src[i] & 0xFFFF) | ((d & (BKT_NODES - 1)) << 16),
                                __float_as_int(vals[i]));
    }
}

__global__ __launch_bounds__(1024) void k45_sort_gather(
        const int* __restrict__ M, const int* __restrict__ bsum, int nblk,
        const int2* __restrict__ spackA, int2* __restrict__ spackB,
        const uint2* __restrict__ feat2,
        const float4* __restrict__ bias4, float4* __restrict__ out4,
        int N, int nbkt) {
    __shared__ int sbs[MAXBSUM];
    __shared__ int hist[BKT_NODES];
    __shared__ int sbuf[BKT_NODES];
    __shared__ int lcur[BKT_NODES];
    __shared__ int2 ls[CAP];
    int b = blockIdx.x;
    int tid = threadIdx.x;
    scan_bsum_wave(bsum, nblk, sbs, tid);
    int j0 = b * NCHUNK;
    int j1 = (b + 1) * NCHUNK;
    int base = M[j0] + sbs[j0 >> 10];
    int end  = M[j1] + sbs[j1 >> 10];
    int cnt = end - base;
    bool inlds = (cnt <= CAP);

    if (tid < BKT_NODES) hist[tid] = 0;
    __syncthreads();
    for (int i = tid; i < cnt; i += 1024)
        atomicAdd(&hist[(spackA[base + i].x >> 16) & (BKT_NODES - 1)], 1);
    __syncthreads();
    if (tid < 64) {
        int h0 = hist[2 * tid], h1 = hist[2 * tid + 1];
        int s = h0 + h1;
        int v = s;
        for (int off = 1; off < 64; off <<= 1) {
            int t = __shfl_up(v, off, 64);
            if (tid >= off) v += t;
        }
        sbuf[2 * tid]     = v - h1;
        sbuf[2 * tid + 1] = v;
        lcur[2 * tid]     = v - s;
        lcur[2 * tid + 1] = v - h1;
    }
    __syncthreads();
    for (int i = tid; i < cnt; i += 1024) {
        int2 r = spackA[base + i];
        int p = atomicAdd(&lcur[(r.x >> 16) & (BKT_NODES - 1)], 1);
        if (inlds) ls[p] = r;
        else       spackB[base + p] = r;
    }
    __syncthreads();

    int wave = tid >> 6, lane = tid & 63;
    int half = lane >> 5;
    int hl   = lane & 31;
    float4 bv = bias4[hl];
    for (int n = wave; n < BKT_NODES; n += 16) {
        int node = (b << BKT_SHIFT) + n;
        if (node >= N) break;
        int lend = sbuf[n];
        int lbeg = lend - hist[n];
        float4 a0 = make_float4(0.f, 0.f, 0.f, 0.f);
        float4 a1 = make_float4(0.f, 0.f, 0.f, 0.f);
        if (inlds) {
            for (int e0 = lbeg; e0 < lend; e0 += 16) {
                int2 p[8];
                uint2 h[8];
#pragma unroll
                for (int j = 0; j < 8; j++)
                    p[j] = ls[min(e0 + 2 * j + half, lend - 1)];
#pragma unroll
                for (int j = 0; j < 8; j++)
                    h[j] = feat2[(size_t)(p[j].x & 0xFFFF) * 32 + hl];
#pragma unroll
                for (int j = 0; j < 8; j++) {
                    float v = (e0 + 2 * j + half < lend) ? __int_as_float(p[j].y) : 0.f;
                    __hip_bfloat162 blo, bhi;
                    __builtin_memcpy(&blo, &h[j].x, 4);
                    __builtin_memcpy(&bhi, &h[j].y, 4);
                    float2 f01 = __bfloat1622float2(blo);
                    float2 f23 = __bfloat1622float2(bhi);
                    if (j & 1) {
                        a1.x += v * f01.x; a1.y += v * f01.y;
                        a1.z += v * f23.x; a1.w += v * f23.y;
                    } else {
                        a0.x += v * f01.x; a0.y += v * f01.y;
                        a0.z += v * f23.x; a0.w += v * f23.y;
                    }
                }
            }
        } else {
            for (int e0 = lbeg; e0 < lend; e0 += 16) {
                int2 p[8];
                uint2 h[8];
#pragma unroll
                for (int j = 0; j < 8; j++)
                    p[j] = spackB[base + min(e0 + 2 * j + half, lend - 1)];
#pragma unroll
                for (int j = 0; j < 8; j++)
                    h[j] = feat2[(size_t)(p[j].x & 0xFFFF) * 32 + hl];
#pragma unroll
                for (int j = 0; j < 8; j++) {
                    float v = (e0 + 2 * j + half < lend) ? __int_as_float(p[j].y) : 0.f;
                    __hip_bfloat162 blo, bhi;
                    __builtin_memcpy(&blo, &h[j].x, 4);
                    __builtin_memcpy(&bhi, &h[j].y, 4);
                    float2 f01 = __bfloat1622float2(blo);
                    float2 f23 = __bfloat1622float2(bhi);
                    if (j & 1) {
                        a1.x += v * f01.x; a1.y += v * f01.y;
                        a1.z += v * f23.x; a1.w += v * f23.y;
                    } else {
                        a0.x += v * f01.x; a0.y += v * f01.y;
                        a0.z += v * f23.x; a0.w += v * f23.y;
                    }
                }
            }
        }
        a0.x += a1.x; a0.y += a1.y; a0.z += a1.z; a0.w += a1.w;
        a0.x += __shfl_xor(a0.x, 32);
        a0.y += __shfl_xor(a0.y, 32);
        a0.z += __shfl_xor(a0.z, 32);
        a0.w += __shfl_xor(a0.w, 32);
        if (half == 0) {
            out4[(size_t)node * 32 + hl] =
                make_float4(a0.x + bv.x, a0.y + bv.y,
                            a0.z + bv.z, a0.w + bv.w);
        }
    }
}

// ---------- last-resort atomic path ----------

__global__ void init_bias_kernel(float4* __restrict__ out,
                                 const float4* __restrict__ bias, int n4) {
    int i = blockIdx.x * blockDim.x + threadIdx.x;
    if (i < n4) out[i] = bias[i & (D4 - 1)];
}

__global__ void spmm_edge_kernel(const int* __restrict__ src,
                                 const int* __restrict__ dst,
                                 const float* __restrict__ vals,
                                 const float4* __restrict__ feat,
                                 float* __restrict__ out, int n_edges) {
    int tid = blockIdx.x * blockDim.x + threadIdx.x;
    int e = tid >> 5;
    int lane = tid & 31;
    if (e >= n_edges) return;
    int s = src[e];
    int d = dst[e];
    float v = vals[e];
    float4 f = feat[(size_t)s * D4 + lane];
    float* o = out + (size_t)d * D_FEAT + lane * 4;
    atomicAdd(o + 0, v * f.x);
    atomicAdd(o + 1, v * f.y);
    atomicAdd(o + 2, v * f.z);
    atomicAdd(o + 3, v * f.w);
}

extern "C" void kernel_launch(void* const* d_in, const int* in_sizes, int n_in,
                              void* d_out, int out_size, void* d_ws, size_t ws_size,
                              hipStream_t stream) {
    const int* edge_index = (const int*)d_in[0];    // (2, E) int32
    const float* edge_vals = (const float*)d_in[1]; // (E,)
    const float* features  = (const float*)d_in[2]; // (N, 128)
    const float* bias      = (const float*)d_in[3]; // (128,)

    int E = in_sizes[1];
    int N = in_sizes[2] / D_FEAT;
    const int* src = edge_index;
    const int* dst = edge_index + E;
    float* out = (float*)d_out;

    int nbkt = (N + BKT_NODES - 1) >> BKT_SHIFT;
    int n4 = N * D_FEAT / 4;
    int chunk = (E + NCHUNK - 1) / NCHUNK;
    int Mpad = ((nbkt * NCHUNK + 1 + 1023) / 1024) * 1024;
    int nblk2 = Mpad / 1024;

    size_t fb_bytes = (size_t)N * D_FEAT * 2;
    size_t sp_bytes = (size_t)E * 8;
    size_t needed = fb_bytes + 2 * sp_bytes + ((size_t)Mpad + nblk2) * 4;

    bool ok = (ws_size >= needed) && (N >= 1) && (N <= 65536) && (E >= 1) &&
              (in_sizes[3] == D_FEAT) && (nbkt <= MAXBKT) && (nblk2 <= MAXBSUM);

    if (ok) {
        char* wp = (char*)d_ws;
        uint2* fb16 = (uint2*)wp;                      wp += fb_bytes;
        int2* spackA = (int2*)wp;                      wp += sp_bytes;
        int2* spackB = (int2*)wp;                      wp += sp_bytes;
        int* M       = (int*)wp;                       wp += (size_t)Mpad * 4;
        int* bsum    = (int*)wp;

        // one-time cooperative capacity query (host-side, no stream ops)
        static int s_cap = -2;                 // -2 = not queried
        if (s_cap == -2) {
            int nb = 0;
            if (hipOccupancyMaxActiveBlocksPerMultiprocessor(
                    &nb, fused_all, 1024, 0) != hipSuccess) nb = 0;
            int cus = 0;
            hipDeviceProp_t prop;
            int dev = 0;
            if (hipGetDevice(&dev) == hipSuccess &&
                hipGetDeviceProperties(&prop, dev) == hipSuccess)
                cus = prop.multiProcessorCount;
            s_cap = (nb > 0 && cus > 0) ? nb * cus : 0;
        }

        bool launched = false;
        if (s_cap >= 64) {
            int G = s_cap < 512 ? s_cap : 512;
            const float4* fin4 = (const float4*)features;
            const float4* bias4 = (const float4*)bias;
            float4* out4 = (float4*)out;
            void* args[] = {
                (void*)&src, (void*)&dst, (void*)&edge_vals, (void*)&E,
                (void*)&chunk, (void*)&nbkt, (void*)&Mpad, (void*)&nblk2,
                (void*)&M, (void*)&bsum, (void*)&spackA, (void*)&spackB,
                (void*)&fin4, (void*)&fb16, (void*)&n4,
                (void*)&bias4, (void*)&out4, (void*)&N };
            hipError_t err = hipLaunchCooperativeKernel(
                fused_all, dim3(G), dim3(1024), args, 0, stream);
            if (err == hipSuccess) launched = true;
            else s_cap = 0;     // never retry cooperative on this device
        }

        if (!launched) {
            k1_hist_cvt<<<NCHUNK + 256, 256, 0, stream>>>(dst, E, chunk, nbkt,
                                                          M, Mpad,
                                                          (const float4*)features,
                                                          fb16, n4);
            k2a_scan<<<nblk2, 1024, 0, stream>>>(M, bsum);
            k3_partition<<<NCHUNK, 512, 0, stream>>>(src, dst, edge_vals, E,
                                                     chunk, nbkt, nblk2,
                                                     M, bsum, spackA);
            k45_sort_gather<<<nbkt, 1024, 0, stream>>>(M, bsum, nblk2,
                                                       spackA, spackB,
                                                       (const uint2*)fb16,
                                                       (const float4*)bias,
                                                       (float4*)out, N, nbkt);
        }
    } else {
        int no4 = out_size / 4;
        {
            int block = 256, grid = (no4 + block - 1) / block;
            init_bias_kernel<<<grid, block, 0, stream>>>((float4*)out,
                                                         (const float4*)bias, no4);
        }
        {
            int block = 256;
            long long total = (long long)E * 32;
            int grid = (int)((total + block - 1) / block);
            spmm_edge_kernel<<<grid, block, 0, stream>>>(src, dst, edge_vals,
                                                         (const float4*)features,
                                                         out, E);
        }
    }
}

// Round 7
// 139.052 us; speedup vs baseline: 1.6248x; 1.0245x over previous
//
#include <hip/hip_runtime.h>
#include <hip/hip_bf16.h>

#define D_FEAT 128
#define D4 (D_FEAT / 4)
#define BKT_SHIFT 7            // 128 nodes per bucket
#define BKT_NODES 128
#define NCHUNK 256             // edge chunks (partition blocks)
#define MAXBKT 512
#define SLOT 5120              // static per-bucket slots == LDS sort capacity

__device__ inline unsigned pack_bf2(float lo, float hi) {
    __hip_bfloat162 h = __float22bfloat162_rn(make_float2(lo, hi));
    unsigned u;
    __builtin_memcpy(&u, &h, 4);
    return u;
}

// ---- KA: blocks < NCHUNK: partition edges into static per-bucket slot
//      regions (LDS chunk-histogram -> one global atomic per (block,bucket)
//      reservation -> LDS-cursor scatter, ~64B write runs). Edges past a
//      bucket's SLOT capacity go to the overflow list (never happens for
//      non-adversarial inputs). Blocks >= NCHUNK: fp32 -> bf16 feature cvt.
__global__ __launch_bounds__(512) void ka_part_cvt(
        const int* __restrict__ src, const int* __restrict__ dst,
        const float* __restrict__ vals, int E, int chunk, int nbkt,
        int* __restrict__ gcur, int* __restrict__ ovcnt, int4* __restrict__ ov,
        int2* __restrict__ spackA,
        const float4* __restrict__ fin4, uint2* __restrict__ fb16, int n4) {
    int c = blockIdx.x;
    int tid = threadIdx.x;
    if (c < NCHUNK) {
        __shared__ int hist[MAXBKT];
        __shared__ int lcur[MAXBKT];
        for (int i = tid; i < nbkt; i += 512) hist[i] = 0;
        __syncthreads();
        int lo = c * chunk;
        int hi = min(lo + chunk, E);
        for (int i = lo + tid; i < hi; i += 512)
            atomicAdd(&hist[dst[i] >> BKT_SHIFT], 1);
        __syncthreads();
        for (int i = tid; i < nbkt; i += 512) {
            int h = hist[i];
            lcur[i] = h ? (i * SLOT + atomicAdd(&gcur[i], h)) : 0;
        }
        __syncthreads();
        for (int i = lo + tid; i < hi; i += 512) {
            int d = dst[i];
            int s = src[i];
            float v = vals[i];
            int bkt = d >> BKT_SHIFT;
            int pos = atomicAdd(&lcur[bkt], 1);
            if (pos - bkt * SLOT < SLOT) {
                spackA[pos] = make_int2((s & 0xFFFF) |
                                        ((d & (BKT_NODES - 1)) << 16),
                                        __float_as_int(v));
            } else {
                int oi = atomicAdd(ovcnt, 1);
                ov[oi] = make_int4(s, d, __float_as_int(v), 0);
            }
        }
    } else {
        int nb = gridDim.x - NCHUNK;
        int idx = (c - NCHUNK) * 512 + tid;
        int stride = nb * 512;
        for (int i = idx; i < n4; i += stride) {
            float4 f = fin4[i];
            uint2 o;
            o.x = pack_bf2(f.x, f.y);
            o.y = pack_bf2(f.z, f.w);
            fb16[i] = o;
        }
    }
}

// ---- KB: per-bucket counting sort INTO LDS + paired gather.
//      cnt comes straight from gcur (clamped to SLOT); no scan machinery,
//      no global sort fallback (SLOT == LDS capacity).
__global__ __launch_bounds__(1024) void kb_sort_gather(
        const int* __restrict__ gcur, const int2* __restrict__ spackA,
        const uint2* __restrict__ feat2,
        const float4* __restrict__ bias4, float4* __restrict__ out4, int N) {
    __shared__ int hist[BKT_NODES];
    __shared__ int sbuf[BKT_NODES];   // inclusive scan (kept for gather)
    __shared__ int lcur[BKT_NODES];
    __shared__ int2 ls[SLOT];
    int b = blockIdx.x;
    int tid = threadIdx.x;
    int cnt = gcur[b];
    if (cnt > SLOT) cnt = SLOT;
    int base = b * SLOT;

    if (tid < BKT_NODES) hist[tid] = 0;
    __syncthreads();
    for (int i = tid; i < cnt; i += 1024)
        atomicAdd(&hist[(spackA[base + i].x >> 16) & (BKT_NODES - 1)], 1);
    __syncthreads();
    // single-wave scan of the 128-entry histogram (2/lane, shfl)
    if (tid < 64) {
        int h0 = hist[2 * tid], h1 = hist[2 * tid + 1];
        int s = h0 + h1;
        int v = s;
        for (int off = 1; off < 64; off <<= 1) {
            int t = __shfl_up(v, off, 64);
            if (tid >= off) v += t;
        }
        sbuf[2 * tid]     = v - h1;   // inclusive at 2l
        sbuf[2 * tid + 1] = v;        // inclusive at 2l+1
        lcur[2 * tid]     = v - s;    // exclusive
        lcur[2 * tid + 1] = v - h1;
    }
    __syncthreads();
    for (int i = tid; i < cnt; i += 1024) {
        int2 r = spackA[base + i];
        int p = atomicAdd(&lcur[(r.x >> 16) & (BKT_NODES - 1)], 1);
        ls[p] = r;
    }
    __syncthreads();

    int wave = tid >> 6, lane = tid & 63;
    int half = lane >> 5;           // 0: even edges, 1: odd edges
    int hl   = lane & 31;           // feature group: feats 4hl..4hl+3
    float4 bv = bias4[hl];
    for (int n = wave; n < BKT_NODES; n += 16) {
        int node = (b << BKT_SHIFT) + n;
        if (node >= N) break;
        int lend = sbuf[n];
        int lbeg = lend - hist[n];
        float4 a0 = make_float4(0.f, 0.f, 0.f, 0.f);
        float4 a1 = make_float4(0.f, 0.f, 0.f, 0.f);
        for (int e0 = lbeg; e0 < lend; e0 += 16) {
            int2 p[8];
            uint2 h[8];
#pragma unroll
            for (int j = 0; j < 8; j++)
                p[j] = ls[min(e0 + 2 * j + half, lend - 1)];
#pragma unroll
            for (int j = 0; j < 8; j++)
                h[j] = feat2[(size_t)(p[j].x & 0xFFFF) * 32 + hl];
#pragma unroll
            for (int j = 0; j < 8; j++) {
                float v = (e0 + 2 * j + half < lend) ?
                          __int_as_float(p[j].y) : 0.f;
                __hip_bfloat162 blo, bhi;
                __builtin_memcpy(&blo, &h[j].x, 4);
                __builtin_memcpy(&bhi, &h[j].y, 4);
                float2 f01 = __bfloat1622float2(blo);
                float2 f23 = __bfloat1622float2(bhi);
                if (j & 1) {
                    a1.x += v * f01.x; a1.y += v * f01.y;
                    a1.z += v * f23.x; a1.w += v * f23.y;
                } else {
                    a0.x += v * f01.x; a0.y += v * f01.y;
                    a0.z += v * f23.x; a0.w += v * f23.y;
                }
            }
        }
        a0.x += a1.x; a0.y += a1.y; a0.z += a1.z; a0.w += a1.w;
        a0.x += __shfl_xor(a0.x, 32);
        a0.y += __shfl_xor(a0.y, 32);
        a0.z += __shfl_xor(a0.z, 32);
        a0.w += __shfl_xor(a0.w, 32);
        if (half == 0) {
            out4[(size_t)node * 32 + hl] =
                make_float4(a0.x + bv.x, a0.y + bv.y,
                            a0.z + bv.z, a0.w + bv.w);
        }
    }
}

// ---- K_over: drain overflow edges (adversarial skew only; exits instantly
//      when ovcnt == 0). Global float atomics over fp32 features.
__global__ __launch_bounds__(256) void k_over(
        const int4* __restrict__ ov, const int* __restrict__ ovcnt,
        const float4* __restrict__ feat4, float* __restrict__ out) {
    int total = *ovcnt;
    long long items = (long long)total * 32;
    long long stride = (long long)gridDim.x * blockDim.x;
    for (long long i = (long long)blockIdx.x * blockDim.x + threadIdx.x;
         i < items; i += stride) {
        int e = (int)(i >> 5);
        int lane = (int)(i & 31);
        int4 r = ov[e];
        float v = __int_as_float(r.z);
        float4 f = feat4[(size_t)r.x * 32 + lane];
        float* o = out + (size_t)r.y * D_FEAT + lane * 4;
        atomicAdd(o + 0, v * f.x);
        atomicAdd(o + 1, v * f.y);
        atomicAdd(o + 2, v * f.z);
        atomicAdd(o + 3, v * f.w);
    }
}

// ---------- last-resort atomic path ----------

__global__ void init_bias_kernel(float4* __restrict__ out,
                                 const float4* __restrict__ bias, int n4) {
    int i = blockIdx.x * blockDim.x + threadIdx.x;
    if (i < n4) out[i] = bias[i & (D4 - 1)];
}

__global__ void spmm_edge_kernel(const int* __restrict__ src,
                                 const int* __restrict__ dst,
                                 const float* __restrict__ vals,
                                 const float4* __restrict__ feat,
                                 float* __restrict__ out, int n_edges) {
    int tid = blockIdx.x * blockDim.x + threadIdx.x;
    int e = tid >> 5;
    int lane = tid & 31;
    if (e >= n_edges) return;
    int s = src[e];
    int d = dst[e];
    float v = vals[e];
    float4 f = feat[(size_t)s * D4 + lane];
    float* o = out + (size_t)d * D_FEAT + lane * 4;
    atomicAdd(o + 0, v * f.x);
    atomicAdd(o + 1, v * f.y);
    atomicAdd(o + 2, v * f.z);
    atomicAdd(o + 3, v * f.w);
}

extern "C" void kernel_launch(void* const* d_in, const int* in_sizes, int n_in,
                              void* d_out, int out_size, void* d_ws, size_t ws_size,
                              hipStream_t stream) {
    const int* edge_index = (const int*)d_in[0];    // (2, E) int32
    const float* edge_vals = (const float*)d_in[1]; // (E,)
    const float* features  = (const float*)d_in[2]; // (N, 128)
    const float* bias      = (const float*)d_in[3]; // (128,)

    int E = in_sizes[1];
    int N = in_sizes[2] / D_FEAT;
    const int* src = edge_index;
    const int* dst = edge_index + E;
    float* out = (float*)d_out;

    int nbkt = (N + BKT_NODES - 1) >> BKT_SHIFT;
    int n4 = N * D_FEAT / 4;
    int chunk = (E + NCHUNK - 1) / NCHUNK;

    // ws: fb16 | spackA[nbkt*SLOT] | ov[E] | gcur[MAXBKT] | ovcnt
    size_t fb_bytes = (size_t)N * D_FEAT * 2;
    size_t spA_bytes = (size_t)nbkt * SLOT * 8;
    size_t ov_bytes = (size_t)E * 16;
    size_t needed = fb_bytes + spA_bytes + ov_bytes + ((size_t)MAXBKT + 1) * 4;

    bool ok = (ws_size >= needed) && (N >= 1) && (N <= 65536) && (E >= 1) &&
              (in_sizes[3] == D_FEAT) && (nbkt <= MAXBKT);

    if (ok) {
        char* wp = (char*)d_ws;
        uint2* fb16 = (uint2*)wp;                      wp += fb_bytes;
        int2* spackA = (int2*)wp;                      wp += spA_bytes;
        int4* ov     = (int4*)wp;                      wp += ov_bytes;
        int* gcur    = (int*)wp;
        int* ovcnt   = gcur + MAXBKT;

        hipMemsetAsync(gcur, 0, ((size_t)MAXBKT + 1) * 4, stream);

        ka_part_cvt<<<NCHUNK + 256, 512, 0, stream>>>(
            src, dst, edge_vals, E, chunk, nbkt,
            gcur, ovcnt, ov, spackA,
            (const float4*)features, fb16, n4);
        kb_sort_gather<<<nbkt, 1024, 0, stream>>>(
            gcur, spackA, (const uint2*)fb16,
            (const float4*)bias, (float4*)out, N);
        k_over<<<128, 256, 0, stream>>>(ov, ovcnt,
                                        (const float4*)features, out);
    } else {
        int no4 = out_size / 4;
        {
            int block = 256, grid = (no4 + block - 1) / block;
            init_bias_kernel<<<grid, block, 0, stream>>>((float4*)out,
                                                         (const float4*)bias, no4);
        }
        {
            int block = 256;
            long long total = (long long)E * 32;
            int grid = (int)((total + block - 1) / block);
            spmm_edge_kernel<<<grid, block, 0, stream>>>(src, dst, edge_vals,
                                                         (const float4*)features,
                                                         out, E);
        }
    }
}

// Round 8
// 135.597 us; speedup vs baseline: 1.6662x; 1.0255x over previous
//
#include <hip/hip_runtime.h>
#include <hip/hip_bf16.h>

#define D_FEAT 128
#define D4 (D_FEAT / 4)
#define BKT_SHIFT 7            // 128 nodes per bucket
#define BKT_NODES 128
#define NCHUNK 256             // edge chunks (partition blocks)
#define MAXBKT 512
#define SLOT 5120              // static per-bucket slots == LDS sort capacity

__device__ inline unsigned pack_bf2(float lo, float hi) {
    __hip_bfloat162 h = __float22bfloat162_rn(make_float2(lo, hi));
    unsigned u;
    __builtin_memcpy(&u, &h, 4);
    return u;
}

// ---- KA: blocks < NCHUNK: partition edges into static per-bucket slot
//      regions (LDS chunk-histogram -> one global atomic per (block,bucket)
//      reservation -> LDS-cursor scatter, ~64B write runs). Edges past a
//      bucket's SLOT capacity go to the overflow list (never happens for
//      non-adversarial inputs). Blocks >= NCHUNK: fp32 -> bf16 feature cvt
//      (uint4 16B stores).
__global__ __launch_bounds__(512) void ka_part_cvt(
        const int* __restrict__ src, const int* __restrict__ dst,
        const float* __restrict__ vals, int E, int chunk, int nbkt,
        int* __restrict__ gcur, int* __restrict__ ovcnt, int4* __restrict__ ov,
        int2* __restrict__ spackA,
        const float4* __restrict__ fin4, uint4* __restrict__ fb4, int n8) {
    int c = blockIdx.x;
    int tid = threadIdx.x;
    if (c < NCHUNK) {
        __shared__ int hist[MAXBKT];
        __shared__ int lcur[MAXBKT];
        for (int i = tid; i < nbkt; i += 512) hist[i] = 0;
        __syncthreads();
        int lo = c * chunk;
        int hi = min(lo + chunk, E);
        for (int i = lo + tid; i < hi; i += 512)
            atomicAdd(&hist[dst[i] >> BKT_SHIFT], 1);
        __syncthreads();
        for (int i = tid; i < nbkt; i += 512) {
            int h = hist[i];
            lcur[i] = h ? (i * SLOT + atomicAdd(&gcur[i], h)) : 0;
        }
        __syncthreads();
        for (int i = lo + tid; i < hi; i += 512) {
            int d = dst[i];
            int s = src[i];
            float v = vals[i];
            int bkt = d >> BKT_SHIFT;
            int pos = atomicAdd(&lcur[bkt], 1);
            if (pos - bkt * SLOT < SLOT) {
                spackA[pos] = make_int2((s & 0xFFFF) |
                                        ((d & (BKT_NODES - 1)) << 16),
                                        __float_as_int(v));
            } else {
                int oi = atomicAdd(ovcnt, 1);
                ov[oi] = make_int4(s, d, __float_as_int(v), 0);
            }
        }
    } else {
        int nb = gridDim.x - NCHUNK;
        int idx = (c - NCHUNK) * 512 + tid;
        int stride = nb * 512;
        for (int i = idx; i < n8; i += stride) {   // one uint4 (8 bf16) each
            float4 a = fin4[2 * i + 0];
            float4 b = fin4[2 * i + 1];
            uint4 o;
            o.x = pack_bf2(a.x, a.y);
            o.y = pack_bf2(a.z, a.w);
            o.z = pack_bf2(b.x, b.y);
            o.w = pack_bf2(b.z, b.w);
            fb4[i] = o;
        }
    }
}

// ---- KB: per-bucket counting sort INTO LDS + quad gather.
//      Gather: 16 lanes per edge, each lane loads uint4 (8 bf16 feats, 16B);
//      4 edges in flight per wave per unroll step -> half the VMEM/LDS
//      instructions of the uint2 scheme. Cross-quarter reduce via
//      __shfl_xor(16|32); lanes of quarter 0 store 32B per node.
__global__ __launch_bounds__(1024) void kb_sort_gather(
        const int* __restrict__ gcur, const int2* __restrict__ spackA,
        const uint4* __restrict__ feat4u,
        const float4* __restrict__ bias4, float4* __restrict__ out4, int N) {
    __shared__ int hist[BKT_NODES];
    __shared__ int sbuf[BKT_NODES];   // inclusive scan (kept for gather)
    __shared__ int lcur[BKT_NODES];
    __shared__ int2 ls[SLOT];
    int b = blockIdx.x;
    int tid = threadIdx.x;
    int cnt = gcur[b];
    if (cnt > SLOT) cnt = SLOT;
    int base = b * SLOT;

    if (tid < BKT_NODES) hist[tid] = 0;
    __syncthreads();
    for (int i = tid; i < cnt; i += 1024)
        atomicAdd(&hist[(spackA[base + i].x >> 16) & (BKT_NODES - 1)], 1);
    __syncthreads();
    // single-wave scan of the 128-entry histogram (2/lane, shfl)
    if (tid < 64) {
        int h0 = hist[2 * tid], h1 = hist[2 * tid + 1];
        int s = h0 + h1;
        int v = s;
        for (int off = 1; off < 64; off <<= 1) {
            int t = __shfl_up(v, off, 64);
            if (tid >= off) v += t;
        }
        sbuf[2 * tid]     = v - h1;   // inclusive at 2l
        sbuf[2 * tid + 1] = v;        // inclusive at 2l+1
        lcur[2 * tid]     = v - s;    // exclusive
        lcur[2 * tid + 1] = v - h1;
    }
    __syncthreads();
    for (int i = tid; i < cnt; i += 1024) {
        int2 r = spackA[base + i];
        int p = atomicAdd(&lcur[(r.x >> 16) & (BKT_NODES - 1)], 1);
        ls[p] = r;
    }
    __syncthreads();

    int wave = tid >> 6, lane = tid & 63;
    int q  = lane >> 4;             // edge slot within group-of-4
    int ql = lane & 15;             // feature chunk: feats 8ql..8ql+7
    float4 bvA = bias4[2 * ql];
    float4 bvB = bias4[2 * ql + 1];
    for (int n = wave; n < BKT_NODES; n += 16) {
        int node = (b << BKT_SHIFT) + n;
        if (node >= N) break;
        int lend = sbuf[n];
        int lbeg = lend - hist[n];
        float4 aA = make_float4(0.f, 0.f, 0.f, 0.f);
        float4 aB = make_float4(0.f, 0.f, 0.f, 0.f);
        for (int e0 = lbeg; e0 < lend; e0 += 16) {
            int2 p[4];
            uint4 h[4];
#pragma unroll
            for (int j = 0; j < 4; j++)
                p[j] = ls[min(e0 + 4 * j + q, lend - 1)];
#pragma unroll
            for (int j = 0; j < 4; j++)
                h[j] = feat4u[(size_t)(p[j].x & 0xFFFF) * 16 + ql];
#pragma unroll
            for (int j = 0; j < 4; j++) {
                float v = (e0 + 4 * j + q < lend) ?
                          __int_as_float(p[j].y) : 0.f;
                __hip_bfloat162 b0, b1, b2, b3;
                __builtin_memcpy(&b0, &h[j].x, 4);
                __builtin_memcpy(&b1, &h[j].y, 4);
                __builtin_memcpy(&b2, &h[j].z, 4);
                __builtin_memcpy(&b3, &h[j].w, 4);
                float2 f0 = __bfloat1622float2(b0);
                float2 f1 = __bfloat1622float2(b1);
                float2 f2 = __bfloat1622float2(b2);
                float2 f3 = __bfloat1622float2(b3);
                aA.x += v * f0.x; aA.y += v * f0.y;
                aA.z += v * f1.x; aA.w += v * f1.y;
                aB.x += v * f2.x; aB.y += v * f2.y;
                aB.z += v * f3.x; aB.w += v * f3.y;
            }
        }
        // reduce across the 4 edge-quarters (lanes q=0..3 hold partials)
#pragma unroll
        for (int m = 16; m <= 32; m <<= 1) {
            aA.x += __shfl_xor(aA.x, m); aA.y += __shfl_xor(aA.y, m);
            aA.z += __shfl_xor(aA.z, m); aA.w += __shfl_xor(aA.w, m);
            aB.x += __shfl_xor(aB.x, m); aB.y += __shfl_xor(aB.y, m);
            aB.z += __shfl_xor(aB.z, m); aB.w += __shfl_xor(aB.w, m);
        }
        if (q == 0) {
            out4[(size_t)node * 32 + 2 * ql] =
                make_float4(aA.x + bvA.x, aA.y + bvA.y,
                            aA.z + bvA.z, aA.w + bvA.w);
            out4[(size_t)node * 32 + 2 * ql + 1] =
                make_float4(aB.x + bvB.x, aB.y + bvB.y,
                            aB.z + bvB.z, aB.w + bvB.w);
        }
    }
}

// ---- K_over: drain overflow edges (adversarial skew only; exits instantly
//      when ovcnt == 0). Global float atomics over fp32 features.
__global__ __launch_bounds__(256) void k_over(
        const int4* __restrict__ ov, const int* __restrict__ ovcnt,
        const float4* __restrict__ feat4, float* __restrict__ out) {
    int total = *ovcnt;
    long long items = (long long)total * 32;
    long long stride = (long long)gridDim.x * blockDim.x;
    for (long long i = (long long)blockIdx.x * blockDim.x + threadIdx.x;
         i < items; i += stride) {
        int e = (int)(i >> 5);
        int lane = (int)(i & 31);
        int4 r = ov[e];
        float v = __int_as_float(r.z);
        float4 f = feat4[(size_t)r.x * 32 + lane];
        float* o = out + (size_t)r.y * D_FEAT + lane * 4;
        atomicAdd(o + 0, v * f.x);
        atomicAdd(o + 1, v * f.y);
        atomicAdd(o + 2, v * f.z);
        atomicAdd(o + 3, v * f.w);
    }
}

// ---------- last-resort atomic path ----------

__global__ void init_bias_kernel(float4* __restrict__ out,
                                 const float4* __restrict__ bias, int n4) {
    int i = blockIdx.x * blockDim.x + threadIdx.x;
    if (i < n4) out[i] = bias[i & (D4 - 1)];
}

__global__ void spmm_edge_kernel(const int* __restrict__ src,
                                 const int* __restrict__ dst,
                                 const float* __restrict__ vals,
                                 const float4* __restrict__ feat,
                                 float* __restrict__ out, int n_edges) {
    int tid = blockIdx.x * blockDim.x + threadIdx.x;
    int e = tid >> 5;
    int lane = tid & 31;
    if (e >= n_edges) return;
    int s = src[e];
    int d = dst[e];
    float v = vals[e];
    float4 f = feat[(size_t)s * D4 + lane];
    float* o = out + (size_t)d * D_FEAT + lane * 4;
    atomicAdd(o + 0, v * f.x);
    atomicAdd(o + 1, v * f.y);
    atomicAdd(o + 2, v * f.z);
    atomicAdd(o + 3, v * f.w);
}

extern "C" void kernel_launch(void* const* d_in, const int* in_sizes, int n_in,
                              void* d_out, int out_size, void* d_ws, size_t ws_size,
                              hipStream_t stream) {
    const int* edge_index = (const int*)d_in[0];    // (2, E) int32
    const float* edge_vals = (const float*)d_in[1]; // (E,)
    const float* features  = (const float*)d_in[2]; // (N, 128)
    const float* bias      = (const float*)d_in[3]; // (128,)

    int E = in_sizes[1];
    int N = in_sizes[2] / D_FEAT;
    const int* src = edge_index;
    const int* dst = edge_index + E;
    float* out = (float*)d_out;

    int nbkt = (N + BKT_NODES - 1) >> BKT_SHIFT;
    int n8 = N * D_FEAT / 8;        // uint4 units in the bf16 table
    int chunk = (E + NCHUNK - 1) / NCHUNK;

    // ws: fb16 | spackA[nbkt*SLOT] | ov[E] | gcur[MAXBKT] | ovcnt
    size_t fb_bytes = (size_t)N * D_FEAT * 2;
    size_t spA_bytes = (size_t)nbkt * SLOT * 8;
    size_t ov_bytes = (size_t)E * 16;
    size_t needed = fb_bytes + spA_bytes + ov_bytes + ((size_t)MAXBKT + 1) * 4;

    bool ok = (ws_size >= needed) && (N >= 1) && (N <= 65536) && (E >= 1) &&
              (in_sizes[3] == D_FEAT) && (nbkt <= MAXBKT);

    if (ok) {
        char* wp = (char*)d_ws;
        uint4* fb16 = (uint4*)wp;                      wp += fb_bytes;
        int2* spackA = (int2*)wp;                      wp += spA_bytes;
        int4* ov     = (int4*)wp;                      wp += ov_bytes;
        int* gcur    = (int*)wp;
        int* ovcnt   = gcur + MAXBKT;

        hipMemsetAsync(gcur, 0, ((size_t)MAXBKT + 1) * 4, stream);

        ka_part_cvt<<<NCHUNK + 256, 512, 0, stream>>>(
            src, dst, edge_vals, E, chunk, nbkt,
            gcur, ovcnt, ov, spackA,
            (const float4*)features, fb16, n8);
        kb_sort_gather<<<nbkt, 1024, 0, stream>>>(
            gcur, spackA, (const uint4*)fb16,
            (const float4*)bias, (float4*)out, N);
        k_over<<<128, 256, 0, stream>>>(ov, ovcnt,
                                        (const float4*)features, out);
    } else {
        int no4 = out_size / 4;
        {
            int block = 256, grid = (no4 + block - 1) / block;
            init_bias_kernel<<<grid, block, 0, stream>>>((float4*)out,
                                                         (const float4*)bias, no4);
        }
        {
            int block = 256;
            long long total = (long long)E * 32;
            int grid = (int)((total + block - 1) / block);
            spmm_edge_kernel<<<grid, block, 0, stream>>>(src, dst, edge_vals,
                                                         (const float4*)features,
                                                         out, E);
        }
    }
}